// Round 1
// baseline (2504.975 us; speedup 1.0000x reference)
//
#include <hip/hip_runtime.h>
#include <hip/hip_bf16.h>

#define NHEADS 16
#define DKV 128
#define BB 2
#define SS 2048
#define DD 2048

// ================= GEMM: C[M,N] = A[M,K] @ W[K,N] + bias =================
// 128x128 tile, BK=16, 256 threads, 8x8 microtile per thread.
// Thread (tx,ty): rows ty*8..+7, cols {tx*4..+3} and {64+tx*4..+3}
// (split columns keep LDS B-reads 2-way (free) instead of 4-way).
#define TBM 128
#define TBN 128
#define TK 16

__device__ __forceinline__ void gemm_body(const float* __restrict__ A,
                                          const float* __restrict__ W,
                                          const float* __restrict__ bias,
                                          float* __restrict__ C,
                                          int M, int N, int K) {
  __shared__ __align__(16) float As[TK][TBM + 4];
  __shared__ __align__(16) float Bs[TK][TBN + 4];
  const int tid = threadIdx.x;
  const int bm = blockIdx.y * TBM;
  const int bn = blockIdx.x * TBN;
  const int tx = tid & 15;
  const int ty = tid >> 4;
  // A loader: row = tid/2, kk = (tid&1)*8 (two float4)
  const int arow = tid >> 1;
  const int akk  = (tid & 1) * 8;
  // B loader: kk = tid/16, n = (tid&15)*8 (two float4)
  const int lkk  = tid >> 4;
  const int ln8  = (tid & 15) * 8;

  float acc[8][8];
#pragma unroll
  for (int i = 0; i < 8; ++i)
#pragma unroll
    for (int j = 0; j < 8; ++j) acc[i][j] = 0.0f;

  for (int k0 = 0; k0 < K; k0 += TK) {
    const float4* ap = (const float4*)(A + (size_t)(bm + arow) * K + k0 + akk);
    float4 a0 = ap[0];
    float4 a1 = ap[1];
    const float4* bp = (const float4*)(W + (size_t)(k0 + lkk) * N + bn + ln8);
    float4 b0 = bp[0];
    float4 b1 = bp[1];
    __syncthreads();  // previous iteration's LDS reads done
    As[akk + 0][arow] = a0.x; As[akk + 1][arow] = a0.y;
    As[akk + 2][arow] = a0.z; As[akk + 3][arow] = a0.w;
    As[akk + 4][arow] = a1.x; As[akk + 5][arow] = a1.y;
    As[akk + 6][arow] = a1.z; As[akk + 7][arow] = a1.w;
    *(float4*)&Bs[lkk][ln8]     = b0;
    *(float4*)&Bs[lkk][ln8 + 4] = b1;
    __syncthreads();
#pragma unroll
    for (int kk = 0; kk < TK; ++kk) {
      float a[8], b[8];
      *(float4*)&a[0] = *(const float4*)&As[kk][ty * 8];
      *(float4*)&a[4] = *(const float4*)&As[kk][ty * 8 + 4];
      *(float4*)&b[0] = *(const float4*)&Bs[kk][tx * 4];
      *(float4*)&b[4] = *(const float4*)&Bs[kk][64 + tx * 4];
#pragma unroll
      for (int i = 0; i < 8; ++i)
#pragma unroll
        for (int j = 0; j < 8; ++j)
          acc[i][j] = fmaf(a[i], b[j], acc[i][j]);
    }
  }

  const int crow = bm + ty * 8;
  const int c0 = bn + tx * 4;
  const int c1 = bn + 64 + tx * 4;
  float bs[8];
#pragma unroll
  for (int j = 0; j < 4; ++j) { bs[j] = bias[c0 + j]; bs[4 + j] = bias[c1 + j]; }
#pragma unroll
  for (int i = 0; i < 8; ++i) {
    float4 o0 = { acc[i][0] + bs[0], acc[i][1] + bs[1],
                  acc[i][2] + bs[2], acc[i][3] + bs[3] };
    float4 o1 = { acc[i][4] + bs[4], acc[i][5] + bs[5],
                  acc[i][6] + bs[6], acc[i][7] + bs[7] };
    float* cp = C + (size_t)(crow + i) * N;
    *(float4*)(cp + c0) = o0;
    *(float4*)(cp + c1) = o1;
  }
}

__global__ __launch_bounds__(256) void gemm_bias_kernel(
    const float* __restrict__ A, const float* __restrict__ W,
    const float* __restrict__ bias, float* __restrict__ C,
    int M, int N, int K) {
  gemm_body(A, W, bias, C, M, N, K);
}

// K and V projections fused: blockIdx.z selects (A, W, bias, C).
__global__ __launch_bounds__(256) void gemm_kv_kernel(
    const float* __restrict__ Ak, const float* __restrict__ Wk,
    const float* __restrict__ bk, float* __restrict__ Ck,
    const float* __restrict__ Av, const float* __restrict__ Wv,
    const float* __restrict__ bv, float* __restrict__ Cv,
    int M, int N, int K) {
  if (blockIdx.z == 0) gemm_body(Ak, Wk, bk, Ck, M, N, K);
  else                 gemm_body(Av, Wv, bv, Cv, M, N, K);
}

// ================= RoPE (in-place on q[B,S,H*128] and k[B,S,128]) =========
__global__ void rope_kernel(float* __restrict__ q, float* __restrict__ k) {
  const int idx = blockIdx.x * blockDim.x + threadIdx.x;
  const int Nq = BB * SS * NHEADS * 64;
  const int Nk = BB * SS * 64;
  float* base;
  int d, pos;
  if (idx < Nq) {
    d = idx & 63;
    int h = (idx >> 6) & (NHEADS - 1);
    int s = (idx >> 10) & (SS - 1);
    int b = idx >> 21;
    pos = s;
    base = q + (((size_t)b * SS + s) * NHEADS + h) * DKV;
  } else if (idx < Nq + Nk) {
    int r = idx - Nq;
    d = r & 63;
    int s = (r >> 6) & (SS - 1);
    int b = r >> 17;
    pos = s;
    base = k + ((size_t)b * SS + s) * DKV;
  } else {
    return;
  }
  float inv = powf(10000.0f, -(float)d * (1.0f / 64.0f));
  float ang = (float)pos * inv;
  float c = cosf(ang);
  float sn = sinf(ang);
  float x1 = base[d];
  float x2 = base[d + 64];
  base[d]      = x1 * c - x2 * sn;
  base[d + 64] = x1 * sn + x2 * c;
}

// ================= Flash attention (causal MQA) ===========================
// grid (S/64, H, B), 256 threads. Q/K/V tiles 64x128 in LDS (pad +4).
// Thread (tx,ty): score rows r0=ty*4..+3, score cols j = tx+16*jj (strided
// so LDS K-row reads are 2-way). Output dims tx*4 and 64+tx*4.
#define BQ 64
#define BKT 64

__global__ __launch_bounds__(256) void flash_kernel(
    const float* __restrict__ q, const float* __restrict__ k,
    const float* __restrict__ v, const unsigned char* __restrict__ mask,
    float* __restrict__ out) {
  const int qt = blockIdx.x;
  const int h  = blockIdx.y;
  const int b  = blockIdx.z;
  __shared__ __align__(16) float Qs[BQ][DKV + 4];
  __shared__ __align__(16) float Ks[BKT][DKV + 4];
  __shared__ __align__(16) float Vs[BKT][DKV + 4];
  __shared__ __align__(16) float Ps[BKT][BQ + 4];   // Ps[j][r] = P[r][j]
  __shared__ float Ms[BKT];
  const int tid = threadIdx.x;
  const int tx = tid & 15;
  const int ty = tid >> 4;
  const int r0 = ty * 4;

  // Load Q tile (rows stride H*128 in global)
  const float* qbase = q + (((size_t)b * SS + (size_t)qt * BQ) * NHEADS + h) * DKV;
#pragma unroll
  for (int i = 0; i < 8; ++i) {
    int f = tid + i * 256;
    int r = f >> 5, c = (f & 31) * 4;
    *(float4*)&Qs[r][c] = *(const float4*)(qbase + (size_t)r * (NHEADS * DKV) + c);
  }

  float O[4][8];
#pragma unroll
  for (int i = 0; i < 4; ++i)
#pragma unroll
    for (int j = 0; j < 8; ++j) O[i][j] = 0.0f;
  float m[4], l[4];
#pragma unroll
  for (int i = 0; i < 4; ++i) { m[i] = -1e30f; l[i] = 0.0f; }

  const float scale = 0.08838834764831845f;  // 1/sqrt(128)

  for (int kt = 0; kt <= qt; ++kt) {
    __syncthreads();  // previous P@V done before overwriting K/V
    const float4* kb = (const float4*)(k + ((size_t)b * SS + (size_t)kt * BKT) * DKV);
    const float4* vb = (const float4*)(v + ((size_t)b * SS + (size_t)kt * BKT) * DKV);
#pragma unroll
    for (int i = 0; i < 8; ++i) {
      int f = tid + i * 256;
      int r = f >> 5, c = (f & 31) * 4;
      *(float4*)&Ks[r][c] = kb[f];
      *(float4*)&Vs[r][c] = vb[f];
    }
    if (tid < BKT) {
      Ms[tid] = mask[(size_t)b * SS + kt * BKT + tid] ? -1e30f : 0.0f;
    }
    __syncthreads();

    // ---- S = Q K^T (4 rows x 4 strided cols per thread) ----
    float sacc[4][4];
#pragma unroll
    for (int i = 0; i < 4; ++i)
#pragma unroll
      for (int j = 0; j < 4; ++j) sacc[i][j] = 0.0f;
    for (int d = 0; d < DKV; d += 4) {
      float4 qa[4], kb4[4];
#pragma unroll
      for (int i = 0; i < 4; ++i) qa[i] = *(const float4*)&Qs[r0 + i][d];
#pragma unroll
      for (int jj = 0; jj < 4; ++jj) kb4[jj] = *(const float4*)&Ks[tx + 16 * jj][d];
#pragma unroll
      for (int i = 0; i < 4; ++i)
#pragma unroll
        for (int jj = 0; jj < 4; ++jj) {
          sacc[i][jj] = fmaf(qa[i].x, kb4[jj].x, sacc[i][jj]);
          sacc[i][jj] = fmaf(qa[i].y, kb4[jj].y, sacc[i][jj]);
          sacc[i][jj] = fmaf(qa[i].z, kb4[jj].z, sacc[i][jj]);
          sacc[i][jj] = fmaf(qa[i].w, kb4[jj].w, sacc[i][jj]);
        }
    }

    const bool diag = (kt == qt);
#pragma unroll
    for (int i = 0; i < 4; ++i)
#pragma unroll
      for (int jj = 0; jj < 4; ++jj) {
        int jl = tx + 16 * jj;
        float s = sacc[i][jj] * scale + Ms[jl];
        if (diag && (jl > r0 + i)) s = -1e30f;
        sacc[i][jj] = s;
      }

    // ---- online softmax ----
    float rm[4];
#pragma unroll
    for (int i = 0; i < 4; ++i)
      rm[i] = fmaxf(fmaxf(sacc[i][0], sacc[i][1]), fmaxf(sacc[i][2], sacc[i][3]));
#pragma unroll
    for (int off = 1; off < 16; off <<= 1)
#pragma unroll
      for (int i = 0; i < 4; ++i)
        rm[i] = fmaxf(rm[i], __shfl_xor(rm[i], off, 64));

    float p[4][4], rs[4], alpha[4];
#pragma unroll
    for (int i = 0; i < 4; ++i) {
      float mn = fmaxf(m[i], rm[i]);
      alpha[i] = __expf(m[i] - mn);
      m[i] = mn;
#pragma unroll
      for (int jj = 0; jj < 4; ++jj) p[i][jj] = __expf(sacc[i][jj] - mn);
      rs[i] = (p[i][0] + p[i][1]) + (p[i][2] + p[i][3]);
    }
#pragma unroll
    for (int off = 1; off < 16; off <<= 1)
#pragma unroll
      for (int i = 0; i < 4; ++i)
        rs[i] += __shfl_xor(rs[i], off, 64);
#pragma unroll
    for (int i = 0; i < 4; ++i) {
      l[i] = l[i] * alpha[i] + rs[i];
#pragma unroll
      for (int j = 0; j < 8; ++j) O[i][j] *= alpha[i];
    }
    // write P transposed: Ps[j][r0..r0+3]
#pragma unroll
    for (int jj = 0; jj < 4; ++jj) {
      float4 pv = { p[0][jj], p[1][jj], p[2][jj], p[3][jj] };
      *(float4*)&Ps[tx + 16 * jj][r0] = pv;
    }
    __syncthreads();

    // ---- O += P @ V ----
#pragma unroll 8
    for (int j = 0; j < BKT; ++j) {
      float4 pj = *(const float4*)&Ps[j][r0];
      float4 v0 = *(const float4*)&Vs[j][tx * 4];
      float4 v1 = *(const float4*)&Vs[j][64 + tx * 4];
      float pr[4] = { pj.x, pj.y, pj.z, pj.w };
#pragma unroll
      for (int i = 0; i < 4; ++i) {
        O[i][0] = fmaf(pr[i], v0.x, O[i][0]);
        O[i][1] = fmaf(pr[i], v0.y, O[i][1]);
        O[i][2] = fmaf(pr[i], v0.z, O[i][2]);
        O[i][3] = fmaf(pr[i], v0.w, O[i][3]);
        O[i][4] = fmaf(pr[i], v1.x, O[i][4]);
        O[i][5] = fmaf(pr[i], v1.y, O[i][5]);
        O[i][6] = fmaf(pr[i], v1.z, O[i][6]);
        O[i][7] = fmaf(pr[i], v1.w, O[i][7]);
      }
    }
  }

  // ---- epilogue: O / l -> out[B,S,H*128] ----
  float* obase = out + ((size_t)b * SS + (size_t)qt * BQ) * (NHEADS * DKV) + h * DKV;
#pragma unroll
  for (int i = 0; i < 4; ++i) {
    float invl = 1.0f / l[i];
    float* orow = obase + (size_t)(r0 + i) * (NHEADS * DKV);
    float4 o0 = { O[i][0] * invl, O[i][1] * invl, O[i][2] * invl, O[i][3] * invl };
    float4 o1 = { O[i][4] * invl, O[i][5] * invl, O[i][6] * invl, O[i][7] * invl };
    *(float4*)(orow + tx * 4) = o0;
    *(float4*)(orow + 64 + tx * 4) = o1;
  }
}

// ================= launch =================================================
extern "C" void kernel_launch(void* const* d_in, const int* in_sizes, int n_in,
                              void* d_out, int out_size, void* d_ws, size_t ws_size,
                              hipStream_t stream) {
  const float* q_in = (const float*)d_in[0];
  const float* k_in = (const float*)d_in[1];
  const float* v_in = (const float*)d_in[2];
  const unsigned char* mask = (const unsigned char*)d_in[3];
  const float* Wq = (const float*)d_in[4];
  const float* bq = (const float*)d_in[5];
  const float* Wk = (const float*)d_in[6];
  const float* bk = (const float*)d_in[7];
  const float* Wv = (const float*)d_in[8];
  const float* bv = (const float*)d_in[9];
  const float* Wo = (const float*)d_in[10];
  const float* bo = (const float*)d_in[11];

  const int M = BB * SS;  // 4096
  float* qp = (float*)d_ws;                          // [M, 2048]
  float* kp = qp + (size_t)M * (NHEADS * DKV);       // [M, 128]
  float* vp = kp + (size_t)M * DKV;                  // [M, 128]
  float* ap = vp + (size_t)M * DKV;                  // [M, 2048]

  gemm_bias_kernel<<<dim3(DD / TBN, M / TBM), 256, 0, stream>>>(
      q_in, Wq, bq, qp, M, DD, DD);
  gemm_kv_kernel<<<dim3(1, M / TBM, 2), 256, 0, stream>>>(
      k_in, Wk, bk, kp, v_in, Wv, bv, vp, M, DKV, DD);
  rope_kernel<<<(BB * SS * (NHEADS + 1) * 64) / 256, 256, 0, stream>>>(qp, kp);
  flash_kernel<<<dim3(SS / BQ, NHEADS, BB), 256, 0, stream>>>(qp, kp, vp, mask, ap);
  gemm_bias_kernel<<<dim3(DD / TBN, M / TBM), 256, 0, stream>>>(
      ap, Wo, bo, (float*)d_out, M, DD, DD);
}

// Round 2
// 728.649 us; speedup vs baseline: 3.4378x; 3.4378x over previous
//
#include <hip/hip_runtime.h>

#define NHEADS 16
#define DKV 128
#define BB 2
#define SS 2048
#define DD 2048

typedef __attribute__((ext_vector_type(8))) short bf16x8;
typedef __attribute__((ext_vector_type(4))) short bf16x4;
typedef __attribute__((ext_vector_type(4))) float f32x4;

__device__ __forceinline__ short f2bf(float x) {
  unsigned u = __builtin_bit_cast(unsigned, x);
  unsigned r = (u + 0x7fffu + ((u >> 16) & 1u)) >> 16;   // RTNE
  return (short)(unsigned short)r;
}
__device__ __forceinline__ float bf2f(short s) {
  unsigned u = ((unsigned)(unsigned short)s) << 16;
  return __builtin_bit_cast(float, u);
}

// ============ weight transpose: W[K][N] fp32 -> Wt[N][K] bf16 =============
__global__ __launch_bounds__(256) void transpose_w(
    const float* __restrict__ W, short* __restrict__ Wt, int K, int N) {
  __shared__ float T[32][33];
  const int nt = blockIdx.x * 32;
  const int kt = blockIdx.y * 32;
  const int tx = threadIdx.x & 31;
  const int ty = threadIdx.x >> 5;  // 0..7
#pragma unroll
  for (int i = 0; i < 4; ++i)
    T[ty + i * 8][tx] = W[(size_t)(kt + ty + i * 8) * N + nt + tx];
  __syncthreads();
#pragma unroll
  for (int i = 0; i < 4; ++i)
    Wt[(size_t)(nt + ty + i * 8) * K + kt + tx] = f2bf(T[tx][ty + i * 8]);
}

// ============ bf16 MFMA GEMM: C[M,N] = A[M,K] @ Bt[N,K]^T + bias ==========
// 128x128 tile, BK=32, 256 threads (4 waves), wave -> 64x64 (4x4 MFMA tiles).
// AMODE 0: A fp32 (convert in staging). AMODE 1: A bf16.
// cmode 0: C fp32 row-major. 1: C bf16 row-major. 2: C bf16 as [B][N][S] (V^T).
#define ASTR 40  // 32 + 8 pad (2-way banks = free)

template <int AMODE>
__global__ __launch_bounds__(256) void gemm_bf16(
    const void* __restrict__ Ap, const short* __restrict__ Bt,
    const float* __restrict__ bias, void* __restrict__ Cp,
    int M, int N, int K, int cmode) {
  __shared__ __align__(16) short As[128 * ASTR];
  __shared__ __align__(16) short Bs[128 * ASTR];
  const int tid = threadIdx.x;
  const int bm = blockIdx.y * 128;
  const int bn = blockIdx.x * 128;
  const int w = tid >> 6, lane = tid & 63;
  const int lm = lane & 15, q4 = lane >> 4;
  const int m0 = (w & 1) * 64, n0 = (w >> 1) * 64;

  f32x4 acc[4][4];
#pragma unroll
  for (int mi = 0; mi < 4; ++mi)
#pragma unroll
    for (int ni = 0; ni < 4; ++ni) acc[mi][ni] = (f32x4){0.f, 0.f, 0.f, 0.f};

  const float* Af = (const float*)Ap;
  const short* Ab = (const short*)Ap;

  for (int k0 = 0; k0 < K; k0 += 32) {
    float4 av[4];
    bf16x8 ab[2], bv[2];
    if (AMODE == 0) {
#pragma unroll
      for (int i = 0; i < 4; ++i) {
        int c = tid + i * 256, r = c >> 3, kc = (c & 7) * 4;
        av[i] = *(const float4*)(Af + (size_t)(bm + r) * K + k0 + kc);
      }
    } else {
#pragma unroll
      for (int i = 0; i < 2; ++i) {
        int c = tid + i * 256, r = c >> 2, kc = (c & 3) * 8;
        ab[i] = *(const bf16x8*)(Ab + (size_t)(bm + r) * K + k0 + kc);
      }
    }
#pragma unroll
    for (int i = 0; i < 2; ++i) {
      int c = tid + i * 256, r = c >> 2, kc = (c & 3) * 8;
      bv[i] = *(const bf16x8*)(Bt + (size_t)(bn + r) * K + k0 + kc);
    }
    __syncthreads();
    if (AMODE == 0) {
#pragma unroll
      for (int i = 0; i < 4; ++i) {
        int c = tid + i * 256, r = c >> 3, kc = (c & 7) * 4;
        bf16x4 t = {f2bf(av[i].x), f2bf(av[i].y), f2bf(av[i].z), f2bf(av[i].w)};
        *(bf16x4*)&As[r * ASTR + kc] = t;
      }
    } else {
#pragma unroll
      for (int i = 0; i < 2; ++i) {
        int c = tid + i * 256, r = c >> 2, kc = (c & 3) * 8;
        *(bf16x8*)&As[r * ASTR + kc] = ab[i];
      }
    }
#pragma unroll
    for (int i = 0; i < 2; ++i) {
      int c = tid + i * 256, r = c >> 2, kc = (c & 3) * 8;
      *(bf16x8*)&Bs[r * ASTR + kc] = bv[i];
    }
    __syncthreads();

    bf16x8 af[4], bf[4];
#pragma unroll
    for (int mi = 0; mi < 4; ++mi)
      af[mi] = *(const bf16x8*)&As[(m0 + mi * 16 + lm) * ASTR + q4 * 8];
#pragma unroll
    for (int ni = 0; ni < 4; ++ni)
      bf[ni] = *(const bf16x8*)&Bs[(n0 + ni * 16 + lm) * ASTR + q4 * 8];
#pragma unroll
    for (int mi = 0; mi < 4; ++mi)
#pragma unroll
      for (int ni = 0; ni < 4; ++ni)
        acc[mi][ni] = __builtin_amdgcn_mfma_f32_16x16x32_bf16(
            af[mi], bf[ni], acc[mi][ni], 0, 0, 0);
  }

#pragma unroll
  for (int mi = 0; mi < 4; ++mi)
#pragma unroll
    for (int ni = 0; ni < 4; ++ni)
#pragma unroll
      for (int reg = 0; reg < 4; ++reg) {
        int rowg = bm + m0 + mi * 16 + q4 * 4 + reg;
        int colg = bn + n0 + ni * 16 + lm;
        float val = acc[mi][ni][reg] + bias[colg];
        if (cmode == 0)
          ((float*)Cp)[(size_t)rowg * N + colg] = val;
        else if (cmode == 1)
          ((short*)Cp)[(size_t)rowg * N + colg] = f2bf(val);
        else  // V^T: [B][N=128][S=2048]
          ((short*)Cp)[((size_t)(rowg >> 11) * DKV + colg) * SS + (rowg & (SS - 1))] =
              f2bf(val);
      }
}

// ============ RoPE in-place on bf16 q[B,S,H,128], k[B,S,128] ==============
__global__ void rope_kernel(short* __restrict__ q, short* __restrict__ k) {
  const int idx = blockIdx.x * blockDim.x + threadIdx.x;
  const int Nq = BB * SS * NHEADS * 64;
  const int Nk = BB * SS * 64;
  short* base;
  int d, pos;
  if (idx < Nq) {
    d = idx & 63;
    int h = (idx >> 6) & (NHEADS - 1);
    int s = (idx >> 10) & (SS - 1);
    int b = idx >> 21;
    pos = s;
    base = q + (((size_t)b * SS + s) * NHEADS + h) * DKV;
  } else if (idx < Nq + Nk) {
    int r = idx - Nq;
    d = r & 63;
    int s = (r >> 6) & (SS - 1);
    int b = r >> 17;
    pos = s;
    base = k + ((size_t)b * SS + s) * DKV;
  } else {
    return;
  }
  float inv = powf(10000.0f, -(float)d * (1.0f / 64.0f));
  float ang = (float)pos * inv;
  float c = cosf(ang);
  float sn = sinf(ang);
  float x1 = bf2f(base[d]);
  float x2 = bf2f(base[d + 64]);
  base[d]      = f2bf(x1 * c - x2 * sn);
  base[d + 64] = f2bf(x1 * sn + x2 * c);
}

// ============ flash attention, bf16 MFMA ==================================
// grid (S/64, H, B), 256 thr = 4 waves; wave owns 16 q-rows. K-tile 64.
// Q in regs; K LDS [64][136]; V^T LDS [128][72]; P via per-wave LDS [16][72].
#define KSTR 136
#define VSTR 72

__global__ __launch_bounds__(256) void flash_kernel(
    const short* __restrict__ q, const short* __restrict__ k,
    const short* __restrict__ vt, const unsigned char* __restrict__ mask,
    short* __restrict__ out) {
  __shared__ __align__(16) short Ks[64 * KSTR];
  __shared__ __align__(16) short Vs[128 * VSTR];
  __shared__ __align__(16) short Ps[64 * VSTR];
  __shared__ float Ms[64];
  const int qt = blockIdx.x, h = blockIdx.y, b = blockIdx.z;
  const int tid = threadIdx.x;
  const int w = tid >> 6, lane = tid & 63;
  const int lm = lane & 15, q4 = lane >> 4;
  const int qrow0 = qt * 64 + w * 16;

  // Q fragments: wave's 16 rows x 128 dk, once per block
  bf16x8 qf[4];
  const short* qbase = q + (((size_t)b * SS + qrow0 + lm) * NHEADS + h) * DKV;
#pragma unroll
  for (int ks = 0; ks < 4; ++ks)
    qf[ks] = *(const bf16x8*)(qbase + ks * 32 + q4 * 8);

  f32x4 O[8];
#pragma unroll
  for (int vi = 0; vi < 8; ++vi) O[vi] = (f32x4){0.f, 0.f, 0.f, 0.f};
  float mrow[4] = {-1e30f, -1e30f, -1e30f, -1e30f};
  float lrow[4] = {0.f, 0.f, 0.f, 0.f};
  const float scale = 0.08838834764831845f;  // 1/sqrt(128)

  for (int kt = 0; kt <= qt; ++kt) {
    __syncthreads();  // previous tile's LDS reads complete
#pragma unroll
    for (int i = 0; i < 4; ++i) {
      int c = tid + i * 256, r = c >> 4, kc = (c & 15) * 8;
      *(bf16x8*)&Ks[r * KSTR + kc] =
          *(const bf16x8*)(k + ((size_t)b * SS + kt * 64 + r) * DKV + kc);
    }
#pragma unroll
    for (int i = 0; i < 4; ++i) {
      int c = tid + i * 256, dv = c >> 3, tc = (c & 7) * 8;
      *(bf16x8*)&Vs[dv * VSTR + tc] =
          *(const bf16x8*)(vt + ((size_t)b * DKV + dv) * SS + kt * 64 + tc);
    }
    if (tid < 64) Ms[tid] = mask[(size_t)b * SS + kt * 64 + tid] ? -1e30f : 0.0f;
    __syncthreads();

    // ---- S = Q K^T : 4 n-tiles x 4 k-steps ----
    f32x4 sacc[4];
#pragma unroll
    for (int ni = 0; ni < 4; ++ni) sacc[ni] = (f32x4){0.f, 0.f, 0.f, 0.f};
#pragma unroll
    for (int ni = 0; ni < 4; ++ni)
#pragma unroll
      for (int ks = 0; ks < 4; ++ks) {
        bf16x8 kf = *(const bf16x8*)&Ks[(ni * 16 + lm) * KSTR + ks * 32 + q4 * 8];
        sacc[ni] = __builtin_amdgcn_mfma_f32_16x16x32_bf16(qf[ks], kf, sacc[ni], 0, 0, 0);
      }

    // ---- scale + pad-mask + causal ----
    float pm[4][4];  // [ni][reg]
#pragma unroll
    for (int ni = 0; ni < 4; ++ni)
#pragma unroll
      for (int reg = 0; reg < 4; ++reg) {
        int colg = kt * 64 + ni * 16 + lm;
        int rowg = qrow0 + q4 * 4 + reg;
        float s = sacc[ni][reg] * scale + Ms[ni * 16 + lm];
        if (colg > rowg) s = -1e30f;
        pm[ni][reg] = s;
      }

    // ---- online softmax (rows owned per-wave; reduce across lane&15) ----
    float rmax[4];
#pragma unroll
    for (int reg = 0; reg < 4; ++reg)
      rmax[reg] = fmaxf(fmaxf(pm[0][reg], pm[1][reg]), fmaxf(pm[2][reg], pm[3][reg]));
#pragma unroll
    for (int off = 1; off < 16; off <<= 1)
#pragma unroll
      for (int reg = 0; reg < 4; ++reg)
        rmax[reg] = fmaxf(rmax[reg], __shfl_xor(rmax[reg], off, 64));

    float alpha[4], rsum[4];
#pragma unroll
    for (int reg = 0; reg < 4; ++reg) {
      float mn = fmaxf(mrow[reg], rmax[reg]);
      alpha[reg] = __expf(mrow[reg] - mn);
      mrow[reg] = mn;
      float rs = 0.f;
#pragma unroll
      for (int ni = 0; ni < 4; ++ni) {
        float p = __expf(pm[ni][reg] - mn);
        pm[ni][reg] = p;
        rs += p;
      }
      rsum[reg] = rs;
    }
#pragma unroll
    for (int off = 1; off < 16; off <<= 1)
#pragma unroll
      for (int reg = 0; reg < 4; ++reg)
        rsum[reg] += __shfl_xor(rsum[reg], off, 64);
#pragma unroll
    for (int reg = 0; reg < 4; ++reg) lrow[reg] = lrow[reg] * alpha[reg] + rsum[reg];
#pragma unroll
    for (int vi = 0; vi < 8; ++vi)
#pragma unroll
      for (int reg = 0; reg < 4; ++reg) O[vi][reg] *= alpha[reg];

    // ---- P -> LDS (per-wave region, no barrier needed) ----
#pragma unroll
    for (int ni = 0; ni < 4; ++ni)
#pragma unroll
      for (int reg = 0; reg < 4; ++reg)
        Ps[(w * 16 + q4 * 4 + reg) * VSTR + ni * 16 + lm] = f2bf(pm[ni][reg]);

    // ---- O += P @ V : 8 n-tiles x 2 k-steps ----
#pragma unroll
    for (int ks2 = 0; ks2 < 2; ++ks2) {
      bf16x8 pf = *(const bf16x8*)&Ps[(w * 16 + lm) * VSTR + ks2 * 32 + q4 * 8];
#pragma unroll
      for (int vi = 0; vi < 8; ++vi) {
        bf16x8 vf = *(const bf16x8*)&Vs[(vi * 16 + lm) * VSTR + ks2 * 32 + q4 * 8];
        O[vi] = __builtin_amdgcn_mfma_f32_16x16x32_bf16(pf, vf, O[vi], 0, 0, 0);
      }
    }
  }

  // ---- epilogue: O/l -> bf16 out[B,S,H*128] ----
  short* ob = out + ((size_t)b * SS + qrow0) * (NHEADS * DKV) + h * DKV;
  float invl[4];
#pragma unroll
  for (int reg = 0; reg < 4; ++reg) invl[reg] = 1.0f / lrow[reg];
#pragma unroll
  for (int vi = 0; vi < 8; ++vi)
#pragma unroll
    for (int reg = 0; reg < 4; ++reg)
      ob[(size_t)(q4 * 4 + reg) * (NHEADS * DKV) + vi * 16 + lm] =
          f2bf(O[vi][reg] * invl[reg]);
}

// ================= launch =================================================
extern "C" void kernel_launch(void* const* d_in, const int* in_sizes, int n_in,
                              void* d_out, int out_size, void* d_ws, size_t ws_size,
                              hipStream_t stream) {
  const float* q_in = (const float*)d_in[0];
  const float* k_in = (const float*)d_in[1];
  const float* v_in = (const float*)d_in[2];
  const unsigned char* mask = (const unsigned char*)d_in[3];
  const float* Wq = (const float*)d_in[4];
  const float* bq = (const float*)d_in[5];
  const float* Wk = (const float*)d_in[6];
  const float* bk = (const float*)d_in[7];
  const float* Wv = (const float*)d_in[8];
  const float* bv = (const float*)d_in[9];
  const float* Wo = (const float*)d_in[10];
  const float* bo = (const float*)d_in[11];

  const int M = BB * SS;  // 4096
  short* Wqt = (short*)d_ws;                       // [2048][2048]
  short* Wot = Wqt + (size_t)DD * DD;              // [2048][2048]
  short* Wkt = Wot + (size_t)DD * DD;              // [128][2048]
  short* Wvt = Wkt + (size_t)DKV * DD;             // [128][2048]
  short* qp  = Wvt + (size_t)DKV * DD;             // [4096][2048] bf16
  short* kp  = qp + (size_t)M * DD;                // [4096][128]  bf16
  short* vt  = kp + (size_t)M * DKV;               // [2][128][2048] bf16 (V^T)
  short* ap  = vt + (size_t)BB * DKV * SS;         // [4096][2048] bf16

  transpose_w<<<dim3(DD / 32, DD / 32), 256, 0, stream>>>(Wq, Wqt, DD, DD);
  transpose_w<<<dim3(DKV / 32, DD / 32), 256, 0, stream>>>(Wk, Wkt, DD, DKV);
  transpose_w<<<dim3(DKV / 32, DD / 32), 256, 0, stream>>>(Wv, Wvt, DD, DKV);
  transpose_w<<<dim3(DD / 32, DD / 32), 256, 0, stream>>>(Wo, Wot, DD, DD);

  gemm_bf16<0><<<dim3(DD / 128, M / 128), 256, 0, stream>>>(
      q_in, Wqt, bq, qp, M, DD, DD, 1);
  gemm_bf16<0><<<dim3(1, M / 128), 256, 0, stream>>>(
      k_in, Wkt, bk, kp, M, DKV, DD, 1);
  gemm_bf16<0><<<dim3(1, M / 128), 256, 0, stream>>>(
      v_in, Wvt, bv, vt, M, DKV, DD, 2);

  rope_kernel<<<(BB * SS * (NHEADS + 1) * 64) / 256, 256, 0, stream>>>(qp, kp);

  flash_kernel<<<dim3(SS / 64, NHEADS, BB), 256, 0, stream>>>(
      qp, kp, vt, mask, ap);

  gemm_bf16<1><<<dim3(DD / 128, M / 128), 256, 0, stream>>>(
      ap, Wot, bo, d_out, M, DD, DD, 0);
}

// Round 3
// 500.153 us; speedup vs baseline: 5.0084x; 1.4569x over previous
//
#include <hip/hip_runtime.h>

#define NHEADS 16
#define DKV 128
#define BB 2
#define SS 2048
#define DD 2048

typedef __attribute__((ext_vector_type(8))) short bf16x8;
typedef __attribute__((ext_vector_type(4))) short bf16x4;
typedef __attribute__((ext_vector_type(4))) float f32x4;

__device__ __forceinline__ short f2bf(float x) {
  unsigned u = __builtin_bit_cast(unsigned, x);
  unsigned r = (u + 0x7fffu + ((u >> 16) & 1u)) >> 16;  // RTNE
  return (short)(unsigned short)r;
}
__device__ __forceinline__ float bf2f(short s) {
  unsigned u = ((unsigned)(unsigned short)s) << 16;
  return __builtin_bit_cast(float, u);
}

// async global->LDS, 16B per lane; LDS dst = base + lane*16 (wave-uniform base)
__device__ __forceinline__ void async16(const void* g, void* l) {
  __builtin_amdgcn_global_load_lds(
      (__attribute__((address_space(1))) void*)g,
      (__attribute__((address_space(3))) void*)l, 16, 0, 0);
}

// ============ fp32 -> bf16 convert (q_in only) ============================
__global__ __launch_bounds__(256) void cvt_q(const float* __restrict__ x,
                                             short* __restrict__ y) {
  int idx = blockIdx.x * 256 + threadIdx.x;
  int g = idx * 8;
  float4 a = *(const float4*)(x + g);
  float4 b = *(const float4*)(x + g + 4);
  bf16x8 o = {f2bf(a.x), f2bf(a.y), f2bf(a.z), f2bf(a.w),
              f2bf(b.x), f2bf(b.y), f2bf(b.z), f2bf(b.w)};
  *(bf16x8*)(y + g) = o;
}

// ============ weight transpose: W[K][N] fp32 -> Wt[N][K] bf16 =============
__global__ __launch_bounds__(256) void transpose_w(
    const float* __restrict__ W, short* __restrict__ Wt, int K, int N) {
  __shared__ float T[32][33];
  const int nt = blockIdx.x * 32;
  const int kt = blockIdx.y * 32;
  const int tx = threadIdx.x & 31;
  const int ty = threadIdx.x >> 5;
#pragma unroll
  for (int i = 0; i < 4; ++i)
    T[ty + i * 8][tx] = W[(size_t)(kt + ty + i * 8) * N + nt + tx];
  __syncthreads();
#pragma unroll
  for (int i = 0; i < 4; ++i)
    Wt[(size_t)(nt + ty + i * 8) * K + kt + tx] = f2bf(T[tx][ty + i * 8]);
}

// ============ MFMA GEMM with async staging ================================
// C[M,N] = A[M,K] @ Bt[N,K]^T (+bias). 128x128 tile, BK=32, 256 thr.
// LDS unpadded [128][32] bf16, 16B-chunk XOR swizzle: phys = logical ^ (row&3).
// AMODE 1: A bf16 via global_load_lds. AMODE 0: A fp32 via VGPR convert.
// cmode 0: fp32+bias. 1: bf16+bias. 2: fp32 partial (split-K, no bias).
template <int AMODE>
__global__ __launch_bounds__(256) void gemm_as(
    const void* __restrict__ Ap, const short* __restrict__ Bt,
    const float* __restrict__ bias, void* __restrict__ Cp,
    int M, int N, int K, int KC, int cmode) {
  __shared__ __align__(16) short As[128 * 32];
  __shared__ __align__(16) short Bs[128 * 32];
  const int tid = threadIdx.x;
  const int bm = blockIdx.y * 128;
  const int bn = blockIdx.x * 128;
  const int kz = blockIdx.z;
  const int w = tid >> 6, lane = tid & 63;
  const int lm = lane & 15, q4 = lane >> 4;
  const int m0 = (w & 1) * 64, n0 = (w >> 1) * 64;

  f32x4 acc[4][4];
#pragma unroll
  for (int mi = 0; mi < 4; ++mi)
#pragma unroll
    for (int ni = 0; ni < 4; ++ni) acc[mi][ni] = (f32x4){0.f, 0.f, 0.f, 0.f};

  const int kbeg = kz * KC;
  const int kend = kbeg + KC;

  for (int k0 = kbeg; k0 < kend; k0 += 32) {
    __syncthreads();  // all waves done reading previous tile
    if (AMODE == 1) {
      const short* Ab = (const short*)Ap;
#pragma unroll
      for (int i = 0; i < 2; ++i) {
        int rA = (w * 2 + i) * 16 + (lane >> 2);
        int cA = (lane & 3) ^ (rA & 3);
        async16(Ab + (size_t)(bm + rA) * K + k0 + cA * 8, &As[(w * 2 + i) * 512]);
      }
    } else {
      const float* Af = (const float*)Ap;
      float4 av[4];
#pragma unroll
      for (int i = 0; i < 4; ++i) {
        int qd = tid + i * 256;
        int r = qd >> 3, cq = qd & 7;
        av[i] = *(const float4*)(Af + (size_t)(bm + r) * K + k0 + cq * 4);
      }
#pragma unroll
      for (int i = 0; i < 4; ++i) {
        int qd = tid + i * 256;
        int r = qd >> 3, cq = qd & 7;
        int ch = cq >> 1, hf = cq & 1;
        int pc = ch ^ (r & 3);
        bf16x4 t = {f2bf(av[i].x), f2bf(av[i].y), f2bf(av[i].z), f2bf(av[i].w)};
        *(bf16x4*)&As[r * 32 + pc * 8 + hf * 4] = t;
      }
    }
#pragma unroll
    for (int i = 0; i < 2; ++i) {
      int rB = (w * 2 + i) * 16 + (lane >> 2);
      int cB = (lane & 3) ^ (rB & 3);
      async16(Bt + (size_t)(bn + rB) * K + k0 + cB * 8, &Bs[(w * 2 + i) * 512]);
    }
    __syncthreads();  // drains vmcnt (global_load_lds) + lgkm

    bf16x8 af[4], bf[4];
#pragma unroll
    for (int mi = 0; mi < 4; ++mi)
      af[mi] = *(const bf16x8*)&As[(m0 + mi * 16 + lm) * 32 + ((q4 ^ (lm & 3)) * 8)];
#pragma unroll
    for (int ni = 0; ni < 4; ++ni)
      bf[ni] = *(const bf16x8*)&Bs[(n0 + ni * 16 + lm) * 32 + ((q4 ^ (lm & 3)) * 8)];
#pragma unroll
    for (int mi = 0; mi < 4; ++mi)
#pragma unroll
      for (int ni = 0; ni < 4; ++ni)
        acc[mi][ni] = __builtin_amdgcn_mfma_f32_16x16x32_bf16(
            af[mi], bf[ni], acc[mi][ni], 0, 0, 0);
  }

  if (cmode == 2) {
    float* Cf = (float*)Cp + (size_t)kz * M * N;
#pragma unroll
    for (int mi = 0; mi < 4; ++mi)
#pragma unroll
      for (int ni = 0; ni < 4; ++ni)
#pragma unroll
        for (int reg = 0; reg < 4; ++reg)
          Cf[(size_t)(bm + m0 + mi * 16 + q4 * 4 + reg) * N +
             (bn + n0 + ni * 16 + lm)] = acc[mi][ni][reg];
  } else {
#pragma unroll
    for (int mi = 0; mi < 4; ++mi)
#pragma unroll
      for (int ni = 0; ni < 4; ++ni)
#pragma unroll
        for (int reg = 0; reg < 4; ++reg) {
          int rowg = bm + m0 + mi * 16 + q4 * 4 + reg;
          int colg = bn + n0 + ni * 16 + lm;
          float val = acc[mi][ni][reg] + bias[colg];
          if (cmode == 0)
            ((float*)Cp)[(size_t)rowg * N + colg] = val;
          else
            ((short*)Cp)[(size_t)rowg * N + colg] = f2bf(val);
        }
  }
}

// ============ KV reduce + bias + K-RoPE + V-transpose =====================
#define SPLITK 4
__global__ __launch_bounds__(256) void kv_reduce(
    const float* __restrict__ kpart, const float* __restrict__ vpart,
    const float* __restrict__ bk, const float* __restrict__ bv,
    short* __restrict__ kp, short* __restrict__ vtb) {
  __shared__ float Kt[64][128];
  __shared__ short Vl[128][68];
  const int tid = threadIdx.x;
  const int r0 = blockIdx.x * 64;
#pragma unroll
  for (int i = 0; i < 32; ++i) {
    int e = tid + i * 256;
    int r = e >> 7, c = e & 127;
    float sk = 0.f, sv = 0.f;
#pragma unroll
    for (int z = 0; z < SPLITK; ++z) {
      sk += kpart[((size_t)z * 4096 + r0 + r) * 128 + c];
      sv += vpart[((size_t)z * 4096 + r0 + r) * 128 + c];
    }
    Kt[r][c] = sk + bk[c];
    Vl[c][r] = f2bf(sv + bv[c]);
  }
  __syncthreads();
#pragma unroll
  for (int i = 0; i < 16; ++i) {
    int e = tid + i * 256;
    int r = e >> 6, d = e & 63;
    float x1 = Kt[r][d], x2 = Kt[r][d + 64];
    float s = (float)((r0 + r) & (SS - 1));
    float ang = s * powf(10000.0f, -(float)d * (1.0f / 64.0f));
    float sn, cs;
    sincosf(ang, &sn, &cs);
    kp[(size_t)(r0 + r) * 128 + d] = f2bf(x1 * cs - x2 * sn);
    kp[(size_t)(r0 + r) * 128 + d + 64] = f2bf(x1 * sn + x2 * cs);
  }
  const int b = r0 >> 11;
  const int j = tid >> 1, soff = (tid & 1) * 32;
  short* dst = vtb + ((size_t)b * 128 + j) * SS + (r0 & (SS - 1)) + soff;
#pragma unroll
  for (int t = 0; t < 4; ++t) {
    bf16x8 tmp;
#pragma unroll
    for (int u = 0; u < 8; ++u) tmp[u] = Vl[j][soff + t * 8 + u];
    *(bf16x8*)(dst + t * 8) = tmp;
  }
}

// ============ flash attention: no-max softmax, async staging, fused RoPE-Q
// grid (S/64, H, B), 256 thr = 4 waves, wave owns 16 q-rows.
// Ks [64][128] bf16 unpadded, swizzle phys=c^(r&7); Vs [128][64] same.
// Ps per-wave [16][72] padded. No per-iter cross-lane ops.
__global__ __launch_bounds__(256) void flash_kernel(
    const short* __restrict__ q, const short* __restrict__ k,
    const short* __restrict__ vt, const unsigned char* __restrict__ mask,
    short* __restrict__ out) {
  __shared__ __align__(16) short Ks[64 * 128];
  __shared__ __align__(16) short Vs[128 * 64];
  __shared__ __align__(16) short Ps[64 * 72];
  __shared__ float Ms[64];
  const int qt = blockIdx.x, h = blockIdx.y, b = blockIdx.z;
  const int tid = threadIdx.x;
  const int w = tid >> 6, lane = tid & 63;
  const int lm = lane & 15, q4 = lane >> 4;
  const int qrow0 = qt * 64 + w * 16;
  const int srow = qrow0 + lm;

  // ---- Q fragments + fused RoPE (pairs d,d+64 are in qf[ks] / qf[ks+2]) --
  bf16x8 qf[4];
  {
    const short* qbase = q + (((size_t)b * SS + srow)) * (NHEADS * DKV) + h * DKV;
    float xv[4][8];
#pragma unroll
    for (int ks = 0; ks < 4; ++ks) {
      bf16x8 raw = *(const bf16x8*)(qbase + ks * 32 + q4 * 8);
#pragma unroll
      for (int j = 0; j < 8; ++j) xv[ks][j] = bf2f(raw[j]);
    }
#pragma unroll
    for (int ks = 0; ks < 2; ++ks)
#pragma unroll
      for (int j = 0; j < 8; ++j) {
        int d = ks * 32 + q4 * 8 + j;
        float ang = (float)srow * powf(10000.0f, -(float)d * (1.0f / 64.0f));
        float sn, cs;
        sincosf(ang, &sn, &cs);
        float x1 = xv[ks][j], x2 = xv[ks + 2][j];
        qf[ks][j] = f2bf(x1 * cs - x2 * sn);
        qf[ks + 2][j] = f2bf(x1 * sn + x2 * cs);
      }
  }

  f32x4 O[8];
#pragma unroll
  for (int vi = 0; vi < 8; ++vi) O[vi] = (f32x4){0.f, 0.f, 0.f, 0.f};
  float lrow[4] = {0.f, 0.f, 0.f, 0.f};
  const float scale = 0.08838834764831845f;  // 1/sqrt(128)

  for (int kt = 0; kt <= qt; ++kt) {
    __syncthreads();  // previous tile's LDS reads complete
#pragma unroll
    for (int i = 0; i < 4; ++i) {
      int rK = (w * 4 + i) * 4 + (lane >> 4);
      int cK = (lane & 15) ^ (rK & 7);
      async16(k + ((size_t)b * SS + kt * 64 + rK) * DKV + cK * 8,
              &Ks[(w * 4 + i) * 512]);
    }
#pragma unroll
    for (int i = 0; i < 4; ++i) {
      int rV = (w * 4 + i) * 8 + (lane >> 3);
      int cV = (lane & 7) ^ (rV & 7);
      async16(vt + ((size_t)b * DKV + rV) * SS + kt * 64 + cV * 8,
              &Vs[(w * 4 + i) * 512]);
    }
    if (tid < 64) Ms[tid] = mask[(size_t)b * SS + kt * 64 + tid] ? -1e30f : 0.0f;
    __syncthreads();  // drains vmcnt + lgkm

    // ---- S = Q K^T ----
    f32x4 sacc[4];
#pragma unroll
    for (int ni = 0; ni < 4; ++ni) sacc[ni] = (f32x4){0.f, 0.f, 0.f, 0.f};
#pragma unroll
    for (int ni = 0; ni < 4; ++ni)
#pragma unroll
      for (int ks = 0; ks < 4; ++ks) {
        bf16x8 kf = *(const bf16x8*)&Ks[(ni * 16 + lm) * 128 +
                                        (((ks * 4 + q4) ^ (lm & 7)) * 8)];
        sacc[ni] = __builtin_amdgcn_mfma_f32_16x16x32_bf16(qf[ks], kf, sacc[ni], 0, 0, 0);
      }

    // ---- p = exp(s*scale + mask), no max subtraction (|s*scale| <~ 12) ---
    const bool diag = (kt == qt);
#pragma unroll
    for (int ni = 0; ni < 4; ++ni) {
      float mbias = Ms[ni * 16 + lm];
      int colg = kt * 64 + ni * 16 + lm;
#pragma unroll
      for (int reg = 0; reg < 4; ++reg) {
        int rowg = qrow0 + q4 * 4 + reg;
        float s = sacc[ni][reg] * scale + mbias;
        if (diag && colg > rowg) s = -1e30f;
        float p = __expf(s);
        lrow[reg] += p;
        Ps[(w * 16 + q4 * 4 + reg) * 72 + ni * 16 + lm] = f2bf(p);
      }
    }

    // ---- O += P @ V (Ps is per-wave; wave-coherent, no barrier) ----
#pragma unroll
    for (int ks2 = 0; ks2 < 2; ++ks2) {
      bf16x8 pf = *(const bf16x8*)&Ps[(w * 16 + lm) * 72 + ks2 * 32 + q4 * 8];
#pragma unroll
      for (int vi = 0; vi < 8; ++vi) {
        bf16x8 vf = *(const bf16x8*)&Vs[(vi * 16 + lm) * 64 +
                                        (((ks2 * 4 + q4) ^ (lm & 7)) * 8)];
        O[vi] = __builtin_amdgcn_mfma_f32_16x16x32_bf16(pf, vf, O[vi], 0, 0, 0);
      }
    }
  }

  // ---- single end-of-kernel l reduction over the 16 lanes of each row ----
#pragma unroll
  for (int off = 1; off < 16; off <<= 1)
#pragma unroll
    for (int reg = 0; reg < 4; ++reg)
      lrow[reg] += __shfl_xor(lrow[reg], off, 64);

  short* ob = out + ((size_t)b * SS + qrow0) * (NHEADS * DKV) + h * DKV;
  float invl[4];
#pragma unroll
  for (int reg = 0; reg < 4; ++reg) invl[reg] = 1.0f / lrow[reg];
#pragma unroll
  for (int vi = 0; vi < 8; ++vi)
#pragma unroll
    for (int reg = 0; reg < 4; ++reg)
      ob[(size_t)(q4 * 4 + reg) * (NHEADS * DKV) + vi * 16 + lm] =
          f2bf(O[vi][reg] * invl[reg]);
}

// ================= launch =================================================
extern "C" void kernel_launch(void* const* d_in, const int* in_sizes, int n_in,
                              void* d_out, int out_size, void* d_ws, size_t ws_size,
                              hipStream_t stream) {
  const float* q_in = (const float*)d_in[0];
  const float* k_in = (const float*)d_in[1];
  const float* v_in = (const float*)d_in[2];
  const unsigned char* mask = (const unsigned char*)d_in[3];
  const float* Wq = (const float*)d_in[4];
  const float* bq = (const float*)d_in[5];
  const float* Wk = (const float*)d_in[6];
  const float* bk = (const float*)d_in[7];
  const float* Wv = (const float*)d_in[8];
  const float* bv = (const float*)d_in[9];
  const float* Wo = (const float*)d_in[10];
  const float* bo = (const float*)d_in[11];

  const int M = BB * SS;  // 4096
  short* Wqt = (short*)d_ws;                   // [2048][2048]
  short* Wot = Wqt + (size_t)DD * DD;          // [2048][2048]
  short* Wkt = Wot + (size_t)DD * DD;          // [128][2048]
  short* Wvt = Wkt + (size_t)DKV * DD;         // [128][2048]
  short* qb  = Wvt + (size_t)DKV * DD;         // [4096][2048] bf16 (input)
  short* qp  = qb + (size_t)M * DD;            // [4096][2048] bf16 (Q proj)
  short* kp  = qp + (size_t)M * DD;            // [4096][128] bf16 (roped K)
  short* vtb = kp + (size_t)M * DKV;           // [2][128][2048] bf16 (V^T)
  float* kpart = (float*)(vtb + (size_t)BB * DKV * SS);  // [4][4096][128]
  float* vpart = kpart + (size_t)SPLITK * M * DKV;       // [4][4096][128]
  short* ap = qb;  // alias: qb dead after Q-proj; flash output reuses it

  cvt_q<<<M * DD / (8 * 256), 256, 0, stream>>>(q_in, qb);
  transpose_w<<<dim3(DD / 32, DD / 32), 256, 0, stream>>>(Wq, Wqt, DD, DD);
  transpose_w<<<dim3(DKV / 32, DD / 32), 256, 0, stream>>>(Wk, Wkt, DD, DKV);
  transpose_w<<<dim3(DKV / 32, DD / 32), 256, 0, stream>>>(Wv, Wvt, DD, DKV);
  transpose_w<<<dim3(DD / 32, DD / 32), 256, 0, stream>>>(Wo, Wot, DD, DD);

  gemm_as<1><<<dim3(DD / 128, M / 128, 1), 256, 0, stream>>>(
      qb, Wqt, bq, qp, M, DD, DD, DD, 1);
  gemm_as<0><<<dim3(1, M / 128, SPLITK), 256, 0, stream>>>(
      k_in, Wkt, nullptr, kpart, M, DKV, DD, DD / SPLITK, 2);
  gemm_as<0><<<dim3(1, M / 128, SPLITK), 256, 0, stream>>>(
      v_in, Wvt, nullptr, vpart, M, DKV, DD, DD / SPLITK, 2);
  kv_reduce<<<M / 64, 256, 0, stream>>>(kpart, vpart, bk, bv, kp, vtb);

  flash_kernel<<<dim3(SS / 64, NHEADS, BB), 256, 0, stream>>>(
      qp, kp, vtb, mask, ap);

  gemm_as<1><<<dim3(DD / 128, M / 128, 1), 256, 0, stream>>>(
      ap, Wot, bo, d_out, M, DD, DD, DD, 0);
}